// Round 3
// baseline (1656.530 us; speedup 1.0000x reference)
//
#include <hip/hip_runtime.h>
#include <hip/hip_bf16.h>

#define B_DIM 16
#define KQ    2048
#define W_DIM 2048
#define D_DIM 128
#define QBLK  64
#define KVB   32
#define NT    (W_DIM / KVB)

typedef float f4 __attribute__((ext_vector_type(4)));
typedef float f32x4 __attribute__((ext_vector_type(4)));
typedef __bf16 bf16x8 __attribute__((ext_vector_type(8)));
typedef unsigned short u16x4 __attribute__((ext_vector_type(4)));
typedef unsigned short u16x8 __attribute__((ext_vector_type(8)));

static __device__ __forceinline__ unsigned short f2bf(float x) {
  __bf16 h = (__bf16)x;
  return __builtin_bit_cast(unsigned short, h);
}

// LDS (single 24KB buffer):
//   [0,     8192)  K1: 32 rows x 128 bf16, row stride 256B, byte ^= ((row&7)<<4)
//   [8192, 16384)  K2: same
//   [16384,24576)  V:  row = d>>1 (128B rows), half h' = (d&1)^((d>>1)&1)^((d>>2)&1),
//                  chunk = gA ^ ((d>>2)&3), slot j=ct*4+i <-> w = 16ct + 4gA + i

__global__ __launch_bounds__(128, 3)
void diffattn(const float* __restrict__ Q1g, const float* __restrict__ Q2g,
              const float* __restrict__ K1g, const float* __restrict__ K2g,
              const float* __restrict__ Vg, const float* __restrict__ lamp,
              float* __restrict__ Og)
{
  __shared__ char smem[24576];

  const int tid  = threadIdx.x;
  const int wave = tid >> 6;    // 0..1
  const int lane = tid & 63;
  const int g    = lane >> 4;   // MFMA 16-lane group
  const int r    = lane & 15;

  // XCD-aware bijective swizzle: 512 blocks = 8 XCDs x 64
  const int wg  = blockIdx.x;
  const int swz = (wg & 7) * 64 + (wg >> 3);
  const int qt  = swz & 31;
  const int b   = swz >> 5;
  const int q0  = qt * QBLK;

  const float scale = 0.08838834764831845f; // 1/sqrt(128)

  // ---- Q fragments: 2 streams x 2 q-groups (32 q-rows per wave)
  bf16x8 qf[2][2][4];
#pragma unroll
  for (int qg = 0; qg < 2; ++qg) {
    const float* q1p = Q1g + ((size_t)b * KQ + q0 + wave * 32 + qg * 16 + r) * D_DIM;
    const float* q2p = Q2g + ((size_t)b * KQ + q0 + wave * 32 + qg * 16 + r) * D_DIM;
#pragma unroll
    for (int kc = 0; kc < 4; ++kc) {
      const int off = kc * 32 + g * 8;
      f4 lo1 = *(const f4*)(q1p + off);
      f4 hi1 = *(const f4*)(q1p + off + 4);
      f4 lo2 = *(const f4*)(q2p + off);
      f4 hi2 = *(const f4*)(q2p + off + 4);
      bf16x8 t1, t2;
#pragma unroll
      for (int j = 0; j < 4; ++j) {
        t1[j]     = (__bf16)(lo1[j] * scale);
        t1[4 + j] = (__bf16)(hi1[j] * scale);
        t2[j]     = (__bf16)(lo2[j] * scale);
        t2[4 + j] = (__bf16)(hi2[j] * scale);
      }
      qf[0][qg][kc] = t1;
      qf[1][qg][kc] = t2;
    }
  }

  const f32x4 vzero = {0.f, 0.f, 0.f, 0.f};
  f32x4 o[2][2][8];
#pragma unroll
  for (int st = 0; st < 2; ++st)
#pragma unroll
    for (int qg = 0; qg < 2; ++qg)
#pragma unroll
      for (int dc = 0; dc < 8; ++dc) o[st][qg][dc] = vzero;

  float m_[2][2], l_[2][2];
#pragma unroll
  for (int st = 0; st < 2; ++st)
#pragma unroll
    for (int qg = 0; qg < 2; ++qg) { m_[st][qg] = -__builtin_inff(); l_[st][qg] = 0.f; }

  const float* k1base = K1g + (size_t)b * W_DIM * D_DIM;
  const float* k2base = K2g + (size_t)b * W_DIM * D_DIM;
  const float* vbase  = Vg  + (size_t)b * W_DIM * D_DIM;

  // ---- staging constants (128 threads) ----
  const int gs = tid >> 5;   // 0..3: K row-block / V pi-group
  const int c8 = tid & 31;   // K f4-column
  const int dq = tid & 31;   // V d-quad

  int kwoff[8], gk[8], gv[8], vwoff[4];
#pragma unroll
  for (int ii = 0; ii < 8; ++ii) {
    const int row = gs * 8 + ii;
    kwoff[ii] = row * 256 + ((c8 * 8) ^ ((row & 7) << 4));
    gk[ii]    = row * D_DIM + c8 * 4;
    const int w = 16 * (ii >> 2) + 4 * gs + (ii & 3);
    gv[ii]    = w * D_DIM + dq * 4;
  }
#pragma unroll
  for (int jj = 0; jj < 4; ++jj) {
    const int hh = (jj & 1) ^ ((jj >> 1) & 1) ^ (dq & 1);
    vwoff[jj] = 16384 + (2 * dq + (jj >> 1)) * 128 + hh * 64 + ((gs ^ (dq & 3)) * 16);
  }

  // ---- compute constants ----
  int koffx[4];
#pragma unroll
  for (int kc = 0; kc < 4; ++kc) koffx[kc] = (kc * 64 + g * 16) ^ ((r & 7) << 4);
  const int vb0 = 16384 + (r >> 1) * 128 +
                  (((r & 1) ^ ((r >> 1) & 1) ^ ((r >> 2) & 1)) * 64) +
                  ((g ^ (r >> 2)) * 16);

  f4 sk1[8], sk2[8], sv[8];

  auto LOADT = [&](int t) {
    const float* p1 = k1base + (size_t)t * KVB * D_DIM;
    const float* p2 = k2base + (size_t)t * KVB * D_DIM;
    const float* pv = vbase  + (size_t)t * KVB * D_DIM;
#pragma unroll
    for (int ii = 0; ii < 8; ++ii) {
      sk1[ii] = *(const f4*)(p1 + gk[ii]);
      sk2[ii] = *(const f4*)(p2 + gk[ii]);
      sv[ii]  = *(const f4*)(pv + gv[ii]);
    }
  };

  auto WRITET = [&]() {
#pragma unroll
    for (int ii = 0; ii < 8; ++ii) {
      u16x4 u1 = { f2bf(sk1[ii][0]), f2bf(sk1[ii][1]), f2bf(sk1[ii][2]), f2bf(sk1[ii][3]) };
      u16x4 u2 = { f2bf(sk2[ii][0]), f2bf(sk2[ii][1]), f2bf(sk2[ii][2]), f2bf(sk2[ii][3]) };
      *(u16x4*)(smem + kwoff[ii])        = u1;
      *(u16x4*)(smem + 8192 + kwoff[ii]) = u2;
    }
#pragma unroll
    for (int jj = 0; jj < 4; ++jj) {
      u16x8 u = { f2bf(sv[0][jj]), f2bf(sv[1][jj]), f2bf(sv[2][jj]), f2bf(sv[3][jj]),
                  f2bf(sv[4][jj]), f2bf(sv[5][jj]), f2bf(sv[6][jj]), f2bf(sv[7][jj]) };
      *(u16x8*)(smem + vwoff[jj]) = u;
    }
  };

  LOADT(0);
  WRITET();
  LOADT(1);
  __syncthreads();

#pragma unroll 1
  for (int t = 0; t < NT; ++t) {
    bf16x8 pa[2][2];

#pragma unroll
    for (int st = 0; st < 2; ++st) {
      const char* kbase = smem + st * 8192;
      f32x4 sa[2][2];
      sa[0][0] = vzero; sa[0][1] = vzero; sa[1][0] = vzero; sa[1][1] = vzero;
#pragma unroll
      for (int kc = 0; kc < 4; ++kc) {
        const bf16x8 a0 = *(const bf16x8*)(kbase + r * 256 + koffx[kc]);
        const bf16x8 a1 = *(const bf16x8*)(kbase + r * 256 + 4096 + koffx[kc]);
#pragma unroll
        for (int qg = 0; qg < 2; ++qg) {
          sa[qg][0] = __builtin_amdgcn_mfma_f32_16x16x32_bf16(a0, qf[st][qg][kc], sa[qg][0], 0, 0, 0);
          sa[qg][1] = __builtin_amdgcn_mfma_f32_16x16x32_bf16(a1, qf[st][qg][kc], sa[qg][1], 0, 0, 0);
        }
      }
#pragma unroll
      for (int qg = 0; qg < 2; ++qg) {
        // lane holds S[w = ct*16 + 4g+i][q = r] for its q-group
        float tm = fmaxf(fmaxf(fmaxf(sa[qg][0][0], sa[qg][0][1]), fmaxf(sa[qg][0][2], sa[qg][0][3])),
                         fmaxf(fmaxf(sa[qg][1][0], sa[qg][1][1]), fmaxf(sa[qg][1][2], sa[qg][1][3])));
        tm = fmaxf(tm, __shfl_xor(tm, 16));
        tm = fmaxf(tm, __shfl_xor(tm, 32));
        if (__any(tm > m_[st][qg])) {
          const float mnew = fmaxf(m_[st][qg], tm);
          const float corr = __expf(m_[st][qg] - mnew);
          m_[st][qg] = mnew;
          l_[st][qg] *= corr;
          f32x4 cv;
#pragma unroll
          for (int i = 0; i < 4; ++i) cv[i] = __shfl(corr, 4 * g + i);
#pragma unroll
          for (int dc = 0; dc < 8; ++dc) o[st][qg][dc] *= cv;
        }
        const float m = m_[st][qg];
        float rs = 0.f;
        bf16x8 pv;
#pragma unroll
        for (int ct = 0; ct < 2; ++ct)
#pragma unroll
          for (int i = 0; i < 4; ++i) {
            const float p = __expf(sa[qg][ct][i] - m);
            rs += p;
            pv[ct * 4 + i] = (__bf16)p;
          }
        rs += __shfl_xor(rs, 16);
        rs += __shfl_xor(rs, 32);
        l_[st][qg] += rs;
        pa[st][qg] = pv;
      }
    }

    // ---- PV: V fragments shared across 2 streams x 2 q-groups ----
#pragma unroll
    for (int dc = 0; dc < 8; ++dc) {
      const bf16x8 vb = *(const bf16x8*)(smem + vb0 + dc * 1024);
      o[0][0][dc] = __builtin_amdgcn_mfma_f32_16x16x32_bf16(pa[0][0], vb, o[0][0][dc], 0, 0, 0);
      o[0][1][dc] = __builtin_amdgcn_mfma_f32_16x16x32_bf16(pa[0][1], vb, o[0][1][dc], 0, 0, 0);
      o[1][0][dc] = __builtin_amdgcn_mfma_f32_16x16x32_bf16(pa[1][0], vb, o[1][0][dc], 0, 0, 0);
      o[1][1][dc] = __builtin_amdgcn_mfma_f32_16x16x32_bf16(pa[1][1], vb, o[1][1][dc], 0, 0, 0);
    }

    __syncthreads();
    if (t + 1 < NT) {
      WRITET();
      if (t + 2 < NT) LOADT(t + 2);
    }
    __syncthreads();
  }

  // ---- epilogue: out = o1/l1 - lam * o2/l2 ----
  const float lam = 1.f / (1.f + __expf(-lamp[0]));
  float* op = Og + ((size_t)b * KQ + q0 + wave * 32) * D_DIM;
#pragma unroll
  for (int qg = 0; qg < 2; ++qg) {
    float w1[4], w2[4];
#pragma unroll
    for (int i = 0; i < 4; ++i) {
      const float l1 = __shfl(l_[0][qg], 4 * g + i);
      const float l2 = __shfl(l_[1][qg], 4 * g + i);
      w1[i] = 1.f / l1;
      w2[i] = lam / l2;
    }
#pragma unroll
    for (int dc = 0; dc < 8; ++dc) {
#pragma unroll
      for (int i = 0; i < 4; ++i) {
        op[(qg * 16 + 4 * g + i) * D_DIM + dc * 16 + r] =
            o[0][qg][dc][i] * w1[i] - o[1][qg][dc][i] * w2[i];
      }
    }
  }
}

extern "C" void kernel_launch(void* const* d_in, const int* in_sizes, int n_in,
                              void* d_out, int out_size, void* d_ws, size_t ws_size,
                              hipStream_t stream) {
  const float* Q1 = (const float*)d_in[0];
  const float* Q2 = (const float*)d_in[1];
  const float* K1 = (const float*)d_in[2];
  const float* K2 = (const float*)d_in[3];
  const float* V  = (const float*)d_in[4];
  const float* lm = (const float*)d_in[5];
  float* O = (float*)d_out;

  dim3 grid(B_DIM * (KQ / QBLK));  // 512 blocks
  dim3 block(128);
  diffattn<<<grid, block, 0, stream>>>(Q1, Q2, K1, K2, V, lm, O);
}

// Round 4
// 134.074 us; speedup vs baseline: 12.3554x; 12.3554x over previous
//
#include <hip/hip_runtime.h>
#include <hip/hip_bf16.h>

#define B_DIM 16
#define KQ    2048
#define W_DIM 2048
#define D_DIM 128
#define QBLK  64
#define KVB   32
#define NT    (W_DIM / KVB)

typedef float f2 __attribute__((ext_vector_type(2)));
typedef float f4 __attribute__((ext_vector_type(4)));
typedef float f32x4 __attribute__((ext_vector_type(4)));
typedef __bf16 bf16x8 __attribute__((ext_vector_type(8)));
typedef unsigned short u16x4 __attribute__((ext_vector_type(4)));
typedef unsigned short u16x8 __attribute__((ext_vector_type(8)));

static __device__ __forceinline__ unsigned short f2bf(float x) {
  __bf16 h = (__bf16)x;
  return __builtin_bit_cast(unsigned short, h);
}

// LDS layout (staged, 24KB used of 32KB):
//   [0,     8192)  K1: 32 w-rows x 128 bf16, row 256B, byte ^= ((row&7)<<4) @16B gran
//   [8192, 16384)  K2: same
//   [16384,24576)  V:  128 d-rows x 64B; within row, 16B chunk c holds w-set
//                  pi_c(j)=16*(j>>2)+4c+(j&3); stored chunk index = c ^ ((d>>1)&3)
//   epilogue reuse: [0,32768) = 64 q-rows x 128 f32 (lam*o2/l2)

__global__ __launch_bounds__(256, 2)
void diffattn(const float* __restrict__ Q1g, const float* __restrict__ Q2g,
              const float* __restrict__ K1g, const float* __restrict__ K2g,
              const float* __restrict__ Vg, const float* __restrict__ lamp,
              float* __restrict__ Og)
{
  __shared__ char smem[32768];

  const int tid  = threadIdx.x;
  const int wv   = tid >> 6;
  const int lane = tid & 63;
  const int g    = lane >> 4;
  const int r    = lane & 15;
  const int s    = wv >> 1;   // stream (0 -> Q1K1, 1 -> Q2K2)
  const int qh   = wv & 1;    // q half (0..1), 32 rows each

  // XCD-aware bijective swizzle: 512 blocks = 8 XCDs x 64
  const int wg  = blockIdx.x;
  const int swz = (wg & 7) * 64 + (wg >> 3);
  const int qt  = swz & 31;
  const int b   = swz >> 5;
  const int q0  = qt * QBLK;

  const float scale = 0.08838834764831845f; // 1/sqrt(128)

  // ---- Q fragments: this wave's stream only, 2 q-groups (32 q-rows)
  const float* Qs = s ? Q2g : Q1g;
  bf16x8 qf[2][4];
#pragma unroll
  for (int qg = 0; qg < 2; ++qg) {
    const float* qp = Qs + ((size_t)b * KQ + q0 + qh * 32 + qg * 16 + r) * D_DIM;
#pragma unroll
    for (int kc = 0; kc < 4; ++kc) {
      const int off = kc * 32 + g * 8;
      f4 lo = *(const f4*)(qp + off);
      f4 hi = *(const f4*)(qp + off + 4);
      bf16x8 tq;
#pragma unroll
      for (int j = 0; j < 4; ++j) {
        tq[j]     = (__bf16)(lo[j] * scale);
        tq[4 + j] = (__bf16)(hi[j] * scale);
      }
      qf[qg][kc] = tq;
    }
  }

  const f32x4 vzero = {0.f, 0.f, 0.f, 0.f};
  f32x4 o[2][8];
#pragma unroll
  for (int qg = 0; qg < 2; ++qg)
#pragma unroll
    for (int dc = 0; dc < 8; ++dc) o[qg][dc] = vzero;

  float m_[2] = {-__builtin_inff(), -__builtin_inff()};
  float l_[2] = {0.f, 0.f};

  const float* k1base = K1g + (size_t)b * W_DIM * D_DIM;
  const float* k2base = K2g + (size_t)b * W_DIM * D_DIM;
  const float* vbase  = Vg  + (size_t)b * W_DIM * D_DIM;

  // ---- staging constants ----
  // K: thread (ks = tid>>5 in 0..7, c8 = tid&31) handles rows ks*4+ii, f4 col c8
  const int ks = tid >> 5;
  const int c8 = tid & 31;
  int gk[4], kw[4];
#pragma unroll
  for (int ii = 0; ii < 4; ++ii) {
    const int row = ks * 4 + ii;
    gk[ii] = row * D_DIM + c8 * 4;
    kw[ii] = row * 256 + ((c8 * 8) ^ ((row & 7) << 4));
  }
  // V: thread (gsv = tid>>6 in 0..3, dd = tid&63) handles chunk gsv for d = 2dd, 2dd+1
  const int gsv = tid >> 6;
  const int dd  = tid & 63;
  int gvv[8];
#pragma unroll
  for (int ii = 0; ii < 8; ++ii) {
    const int w = 16 * (ii >> 2) + 4 * gsv + (ii & 3);
    gvv[ii] = w * D_DIM + 2 * dd;
  }
  int vw[2];
#pragma unroll
  for (int jj = 0; jj < 2; ++jj)
    vw[jj] = 16384 + (2 * dd + jj) * 64 + ((gsv ^ (dd & 3)) << 4);

  // ---- compute constants ----
  int koffx[4];
#pragma unroll
  for (int kc = 0; kc < 4; ++kc) koffx[kc] = (kc * 64 + g * 16) ^ ((r & 7) << 4);
  const int kb0 = s * 8192 + r * 256;
  const int vr0 = 16384 + r * 64 + ((g ^ ((r >> 1) & 3)) << 4);

  f4 sk1[4], sk2[4];
  f2 sv[8];

  auto LOADT = [&](int t) {
    const float* p1 = k1base + (size_t)t * KVB * D_DIM;
    const float* p2 = k2base + (size_t)t * KVB * D_DIM;
    const float* pv = vbase  + (size_t)t * KVB * D_DIM;
#pragma unroll
    for (int ii = 0; ii < 4; ++ii) {
      sk1[ii] = *(const f4*)(p1 + gk[ii]);
      sk2[ii] = *(const f4*)(p2 + gk[ii]);
    }
#pragma unroll
    for (int ii = 0; ii < 8; ++ii)
      sv[ii] = *(const f2*)(pv + gvv[ii]);
  };

  auto WRITET = [&]() {
#pragma unroll
    for (int ii = 0; ii < 4; ++ii) {
      u16x4 u1 = { f2bf(sk1[ii][0]), f2bf(sk1[ii][1]), f2bf(sk1[ii][2]), f2bf(sk1[ii][3]) };
      u16x4 u2 = { f2bf(sk2[ii][0]), f2bf(sk2[ii][1]), f2bf(sk2[ii][2]), f2bf(sk2[ii][3]) };
      *(u16x4*)(smem + kw[ii])        = u1;
      *(u16x4*)(smem + 8192 + kw[ii]) = u2;
    }
#pragma unroll
    for (int jj = 0; jj < 2; ++jj) {
      u16x8 u = { f2bf(sv[0][jj]), f2bf(sv[1][jj]), f2bf(sv[2][jj]), f2bf(sv[3][jj]),
                  f2bf(sv[4][jj]), f2bf(sv[5][jj]), f2bf(sv[6][jj]), f2bf(sv[7][jj]) };
      *(u16x8*)(smem + vw[jj]) = u;
    }
  };

  LOADT(0);
  WRITET();
  LOADT(1);
  __syncthreads();

#pragma unroll 1
  for (int t = 0; t < NT; ++t) {
    // ---- QK^T for this wave's stream: S[w][q], 32w x 32q ----
    f32x4 sa[2][2];
    sa[0][0] = vzero; sa[0][1] = vzero; sa[1][0] = vzero; sa[1][1] = vzero;
#pragma unroll
    for (int kc = 0; kc < 4; ++kc) {
      const bf16x8 a0 = *(const bf16x8*)(smem + kb0 + koffx[kc]);
      const bf16x8 a1 = *(const bf16x8*)(smem + kb0 + 4096 + koffx[kc]);
#pragma unroll
      for (int qg = 0; qg < 2; ++qg) {
        sa[qg][0] = __builtin_amdgcn_mfma_f32_16x16x32_bf16(a0, qf[qg][kc], sa[qg][0], 0, 0, 0);
        sa[qg][1] = __builtin_amdgcn_mfma_f32_16x16x32_bf16(a1, qf[qg][kc], sa[qg][1], 0, 0, 0);
      }
    }

    // ---- online softmax per q-group; P packed into PV A-fragments ----
    bf16x8 pa[2];
#pragma unroll
    for (int qg = 0; qg < 2; ++qg) {
      float tm = fmaxf(fmaxf(fmaxf(sa[qg][0][0], sa[qg][0][1]), fmaxf(sa[qg][0][2], sa[qg][0][3])),
                       fmaxf(fmaxf(sa[qg][1][0], sa[qg][1][1]), fmaxf(sa[qg][1][2], sa[qg][1][3])));
      tm = fmaxf(tm, __shfl_xor(tm, 16));
      tm = fmaxf(tm, __shfl_xor(tm, 32));
      if (__any(tm > m_[qg])) {
        const float mnew = fmaxf(m_[qg], tm);
        const float corr = __expf(m_[qg] - mnew);
        m_[qg] = mnew;
        l_[qg] *= corr;
        f32x4 cv;
#pragma unroll
        for (int i = 0; i < 4; ++i) cv[i] = __shfl(corr, 4 * g + i);
#pragma unroll
        for (int dc = 0; dc < 8; ++dc) o[qg][dc] *= cv;
      }
      const float m = m_[qg];
      float rs = 0.f;
      bf16x8 pv;
#pragma unroll
      for (int wt = 0; wt < 2; ++wt)
#pragma unroll
        for (int i = 0; i < 4; ++i) {
          const float p = __expf(sa[qg][wt][i] - m);
          rs += p;
          pv[wt * 4 + i] = (__bf16)p;   // slot j' = wt*4+i  <->  w = 16wt + 4g + i
        }
      rs += __shfl_xor(rs, 16);
      rs += __shfl_xor(rs, 32);
      l_[qg] += rs;
      pa[qg] = pv;
    }

    // ---- PV: V fragments shared across both q-groups ----
#pragma unroll
    for (int dc = 0; dc < 8; ++dc) {
      const bf16x8 vb = *(const bf16x8*)(smem + vr0 + dc * 1024);
      o[0][dc] = __builtin_amdgcn_mfma_f32_16x16x32_bf16(pa[0], vb, o[0][dc], 0, 0, 0);
      o[1][dc] = __builtin_amdgcn_mfma_f32_16x16x32_bf16(pa[1], vb, o[1][dc], 0, 0, 0);
    }

    __syncthreads();
    if (t + 1 < NT) {
      WRITET();
      if (t + 2 < NT) LOADT(t + 2);
    }
    __syncthreads();
  }

  // ---- epilogue: combine streams via LDS ----
  const float lam = 1.f / (1.f + __expf(-lamp[0]));
  if (s == 1) {
#pragma unroll
    for (int qg = 0; qg < 2; ++qg) {
      float w2[4];
#pragma unroll
      for (int i = 0; i < 4; ++i) w2[i] = lam / __shfl(l_[qg], 4 * g + i);
#pragma unroll
      for (int dc = 0; dc < 8; ++dc)
#pragma unroll
        for (int i = 0; i < 4; ++i) {
          const int ql = qh * 32 + qg * 16 + 4 * g + i;
          *(float*)(smem + ql * 512 + (dc * 16 + r) * 4) = o[qg][dc][i] * w2[i];
        }
    }
  }
  __syncthreads();
  if (s == 0) {
    float* op = Og + ((size_t)b * KQ + q0 + qh * 32) * D_DIM;
#pragma unroll
    for (int qg = 0; qg < 2; ++qg) {
      float w1[4];
#pragma unroll
      for (int i = 0; i < 4; ++i) w1[i] = 1.f / __shfl(l_[qg], 4 * g + i);
#pragma unroll
      for (int dc = 0; dc < 8; ++dc)
#pragma unroll
        for (int i = 0; i < 4; ++i) {
          const int ql = qh * 32 + qg * 16 + 4 * g + i;
          const float o2v = *(const float*)(smem + ql * 512 + (dc * 16 + r) * 4);
          op[(qg * 16 + 4 * g + i) * D_DIM + dc * 16 + r] = o[qg][dc][i] * w1[i] - o2v;
        }
    }
  }
}

extern "C" void kernel_launch(void* const* d_in, const int* in_sizes, int n_in,
                              void* d_out, int out_size, void* d_ws, size_t ws_size,
                              hipStream_t stream) {
  const float* Q1 = (const float*)d_in[0];
  const float* Q2 = (const float*)d_in[1];
  const float* K1 = (const float*)d_in[2];
  const float* K2 = (const float*)d_in[3];
  const float* V  = (const float*)d_in[4];
  const float* lm = (const float*)d_in[5];
  float* O = (float*)d_out;

  dim3 grid(B_DIM * (KQ / QBLK));  // 512 blocks, 2/CU
  dim3 block(256);
  diffattn<<<grid, block, 0, stream>>>(Q1, Q2, K1, K2, V, lm, O);
}